// Round 4
// baseline (182.534 us; speedup 1.0000x reference)
//
#include <hip/hip_runtime.h>
#include <hip/hip_cooperative_groups.h>
#include <cstddef>
#include <cstdint>

namespace cg = cooperative_groups;

// Problem constants (match reference setup_inputs)
#define HH    128
#define WW    128
#define CC    392           // K*K*8 = 49*8
#define NPIX  (HH*WW)       // 16384
#define NROI  2048
#define PSK   7
#define NBIN  49
#define LAMDA 0.1f

// Fragment-major layouts (conv reads operands DIRECTLY from global -> VGPR):
//  A: Fh2[y(130)][kc(7)][q(8)][x(130)][8 halves]   (x-major per k-slice)
//  B: Btf[seg(9)][kc(7)][kh(2)][cob(25)][quad(4)][fr(16)][8 halves]
#define XP      130
#define FH2TOT  (130*7*8*130)   // 946400 half8 units = 15.14 MB
#define BKHS    12800           // halves per ((seg*7+kc)*2+kh) slice = 25*4*128
#define BSEGS   (14*BKHS)       // seg stride (index step 14)
#define BTFH    (9*7*2*BKHS)    // 1,612,800 halves = 3.23 MB

// mega-kernel geometry: 448 blocks x 256 threads (4 waves), no conv LDS
#define NBLK    448
#define NTHR    256
#define GSTRIDE (NBLK*NTHR)
#define WTILES  (9*14*13)               // 1638 weight 32x32 tiles
#define POOL8   (NROI*NBIN*8)           // 802816 = 3136*256 exactly

typedef _Float16 half8   __attribute__((ext_vector_type(8)));
typedef _Float16 half4v  __attribute__((ext_vector_type(4)));
typedef _Float16 half2v  __attribute__((ext_vector_type(2)));
typedef float    floatx4 __attribute__((ext_vector_type(4)));

// ---------------------------------------------------------------------------
// Prep 1: features fp32 [128,128,392] -> f16 Fh2[y][kc][q][x][8] with zero
// halo (y,x in halo coords 0..129; image pixel = coord-1). Coalesced writes.
// ---------------------------------------------------------------------------
__device__ __forceinline__ void prep_features(const float* __restrict__ F,
                                              _Float16* __restrict__ Fh2,
                                              int gtid, int stride) {
  for (int idx = gtid; idx < FH2TOT; idx += stride) {
    const int x = idx % XP;
    int r = idx / XP;
    const int q = r & 7; r >>= 3;
    const int kc = r % 7;
    const int y = r / 7;
    const int c = kc * 64 + q * 8;
    half8 h;
#pragma unroll
    for (int i = 0; i < 8; ++i) h[i] = (_Float16)0.f;
    if (y >= 1 && y <= HH && x >= 1 && x <= WW && c < CC) {
      const float* src = F + ((size_t)(y - 1) * WW + (x - 1)) * CC + c;
      const float4 v0 = *(const float4*)src;
      const float4 v1 = *(const float4*)(src + 4);
      h[0] = (_Float16)v0.x; h[1] = (_Float16)v0.y;
      h[2] = (_Float16)v0.z; h[3] = (_Float16)v0.w;
      h[4] = (_Float16)v1.x; h[5] = (_Float16)v1.y;
      h[6] = (_Float16)v1.z; h[7] = (_Float16)v1.w;
    }
    *(half8*)(Fh2 + (size_t)idx * 8) = h;
  }
}

// ---------------------------------------------------------------------------
// Prep 2: weights fp32 [9,392,392] (seg,ci,co) -> f16 fragment-major Btf via
// 32x32 LDS tile transpose. ci zero-padded to 448, co to 400.
// Btf[(((seg*7+kc)*2+kh)*25+cob)*4+quad][fr][8], ci = kc*64+kh*32+quad*8+e.
// ---------------------------------------------------------------------------
__device__ __forceinline__ void prep_weights(const float* __restrict__ Wt,
                                             _Float16* __restrict__ Btf,
                                             float (*tile)[33],
                                             int bid, int t, int bdim, int nblocks) {
  for (int tl = bid; tl < WTILES; tl += nblocks) {
    const int seg = tl / (14 * 13);
    const int rem = tl - seg * (14 * 13);
    const int cit = rem / 13;         // ci tile 0..13
    const int cot = rem - cit * 13;   // co tile 0..12
    const int ci0 = cit * 32, co0 = cot * 32;
    __syncthreads();                  // protect tile reuse across iterations
    for (int idx = t; idx < 1024; idx += bdim) {
      const int lr = idx >> 5;        // local ci
      const int lc = idx & 31;        // local co (fast -> coalesced read)
      const int ci = ci0 + lr, co = co0 + lc;
      float v = 0.f;
      if (ci < CC && co < CC) v = Wt[((size_t)seg * CC + ci) * CC + co];
      tile[lr][lc] = v;
    }
    __syncthreads();
    for (int u = t; u < 128; u += bdim) {
      const int lr  = u & 31;         // local co (fast -> coalesced write)
      const int lc8 = u >> 5;         // ci octet within tile
      const int co = co0 + lr;
      if (co < 400) {
        const int cib = ci0 + lc8 * 8;
        const int kc = cib >> 6, kh = (cib >> 5) & 1, qd = (cib >> 3) & 3;
        half8 v;
#pragma unroll
        for (int e = 0; e < 8; ++e) v[e] = (_Float16)tile[lc8 * 8 + e][lr];
        const size_t dst = ((((size_t)(seg * 7 + kc) * 2 + kh) * 25 + (co >> 4)) * 4 + qd) * 128
                         + (size_t)(co & 15) * 8;
        *(half8*)(Btf + dst) = v;
      }
    }
  }
}

// ---------------------------------------------------------------------------
// Fat conv wave-tile: 64M x 64N per wave, block = 2x2 waves = 128M x 128N.
// NO LDS, NO barriers: fragments loaded straight from fragment-major global
// layouts (coalesced), latency hidden by ILP + free-running waves.
// Substep order (dyi, kc, dxs, kh) identical to prior rounds -> same numerics.
// ---------------------------------------------------------------------------
__device__ __forceinline__ void conv_fat(const _Float16* __restrict__ Fh2,
                                         const _Float16* __restrict__ Btf,
                                         _Float16* __restrict__ OM,
                                         int ya, int col0, int t) {
  const int L = t & 63, w = t >> 6;
  const int fr = L & 15, quad = L >> 4;
  const int wm = (w >> 1) * 64, wn = (w & 1) * 64;
  const int cob0 = (col0 + wn) >> 4;

  floatx4 acc[4][4];
#pragma unroll
  for (int i = 0; i < 4; ++i)
#pragma unroll
    for (int j = 0; j < 4; ++j) {
      floatx4 z = {0.f, 0.f, 0.f, 0.f};
      acc[i][j] = z;
    }

#pragma unroll 1
  for (int dyi = 0; dyi < 3; ++dyi) {
    const int fy = ya + dyi;           // halo row coord (out image row + dy + 1)
#pragma unroll 1
    for (int kc = 0; kc < 7; ++kc) {
      const _Float16* Ap = Fh2 + (((size_t)(fy * 7 + kc) * 8 + quad) * XP + wm + fr) * 8;
      const _Float16* Bq = Btf + (size_t)((dyi * 3 * 7 + kc) * 2) * BKHS
                               + (size_t)cob0 * 512 + quad * 128 + fr * 8;
#pragma unroll
      for (int dxs = 0; dxs < 3; ++dxs) {
        const _Float16* Bp = Bq + (size_t)dxs * BSEGS;
        half8 a0[4], b0[4];
#pragma unroll
        for (int mt = 0; mt < 4; ++mt)
          a0[mt] = *(const half8*)(Ap + (mt * 16 + dxs) * 8);
#pragma unroll
        for (int nt = 0; nt < 4; ++nt)
          b0[nt] = *(const half8*)(Bp + nt * 512);
#pragma unroll
        for (int mt = 0; mt < 4; ++mt)
#pragma unroll
          for (int nt = 0; nt < 4; ++nt)
            acc[mt][nt] = __builtin_amdgcn_mfma_f32_16x16x32_f16(a0[mt], b0[nt], acc[mt][nt], 0, 0, 0);
        half8 a1[4], b1[4];
#pragma unroll
        for (int mt = 0; mt < 4; ++mt)
          a1[mt] = *(const half8*)(Ap + (mt * 16 + dxs) * 8 + 4 * XP * 8);
#pragma unroll
        for (int nt = 0; nt < 4; ++nt)
          b1[nt] = *(const half8*)(Bp + 25 * 512 + nt * 512);
#pragma unroll
        for (int mt = 0; mt < 4; ++mt)
#pragma unroll
          for (int nt = 0; nt < 4; ++nt)
            acc[mt][nt] = __builtin_amdgcn_mfma_f32_16x16x32_f16(a1[mt], b1[nt], acc[mt][nt], 0, 0, 0);
      }
    }
  }

  // epilogue: C/D mapping col=lane&15, row=(lane>>4)*4+reg
#pragma unroll
  for (int mt = 0; mt < 4; ++mt) {
    const int xb = wm + mt * 16 + quad * 4;
#pragma unroll
    for (int nt = 0; nt < 4; ++nt) {
      const int col = col0 + wn + nt * 16 + fr;
      if (col < CC) {
#pragma unroll
        for (int r = 0; r < 4; ++r)
          OM[(size_t)(ya * 128 + xb + r) * CC + col] = (_Float16)acc[mt][nt][r];
      }
    }
  }
}

// ---------------------------------------------------------------------------
// Thin conv wave-tile: 64M x 16N (cols 384..399, real 384..391). Block = 4
// waves covering 2 image rows x 2 x-halves.
// ---------------------------------------------------------------------------
__device__ __forceinline__ void conv_thin(const _Float16* __restrict__ Fh2,
                                          const _Float16* __restrict__ Btf,
                                          _Float16* __restrict__ OM,
                                          int tb, int t) {
  const int L = t & 63, w = t >> 6;
  const int fr = L & 15, quad = L >> 4;
  const int ya = tb * 2 + (w >> 1);
  const int wm = (w & 1) * 64;

  floatx4 acc[4];
#pragma unroll
  for (int i = 0; i < 4; ++i) {
    floatx4 z = {0.f, 0.f, 0.f, 0.f};
    acc[i] = z;
  }

#pragma unroll 1
  for (int dyi = 0; dyi < 3; ++dyi) {
    const int fy = ya + dyi;
#pragma unroll 1
    for (int kc = 0; kc < 7; ++kc) {
      const _Float16* Ap = Fh2 + (((size_t)(fy * 7 + kc) * 8 + quad) * XP + wm + fr) * 8;
      const _Float16* Bq = Btf + (size_t)((dyi * 3 * 7 + kc) * 2) * BKHS
                               + (size_t)24 * 512 + quad * 128 + fr * 8;
#pragma unroll
      for (int dxs = 0; dxs < 3; ++dxs) {
        const _Float16* Bp = Bq + (size_t)dxs * BSEGS;
        half8 a0[4];
#pragma unroll
        for (int mt = 0; mt < 4; ++mt)
          a0[mt] = *(const half8*)(Ap + (mt * 16 + dxs) * 8);
        const half8 b0 = *(const half8*)(Bp);
#pragma unroll
        for (int mt = 0; mt < 4; ++mt)
          acc[mt] = __builtin_amdgcn_mfma_f32_16x16x32_f16(a0[mt], b0, acc[mt], 0, 0, 0);
        half8 a1[4];
#pragma unroll
        for (int mt = 0; mt < 4; ++mt)
          a1[mt] = *(const half8*)(Ap + (mt * 16 + dxs) * 8 + 4 * XP * 8);
        const half8 b1 = *(const half8*)(Bp + 25 * 512);
#pragma unroll
        for (int mt = 0; mt < 4; ++mt)
          acc[mt] = __builtin_amdgcn_mfma_f32_16x16x32_f16(a1[mt], b1, acc[mt], 0, 0, 0);
      }
    }
  }

#pragma unroll
  for (int mt = 0; mt < 4; ++mt) {
    const int xb = wm + mt * 16 + quad * 4;
    const int col = 384 + fr;
    if (col < CC) {
#pragma unroll
      for (int r = 0; r < 4; ++r)
        OM[(size_t)(ya * 128 + xb + r) * CC + col] = (_Float16)acc[mt][r];
    }
  }
}

// ---------------------------------------------------------------------------
// Conv block decode (on XCD-swizzled bid2): bid2<384 -> fat (ya=bid2/3,
// col0=(bid2%3)*128, m-major so each XCD gets ~19 consecutive rows);
// else thin block (2 rows).
// ---------------------------------------------------------------------------
__device__ __forceinline__ void conv_dispatch(const _Float16* __restrict__ Fh2,
                                              const _Float16* __restrict__ Btf,
                                              _Float16* __restrict__ OM,
                                              int bid2, int t) {
  if (bid2 < 384)
    conv_fat(Fh2, Btf, OM, bid2 / 3, (bid2 % 3) * 128, t);
  else
    conv_thin(Fh2, Btf, OM, bid2 - 384, t);
}

// ---------------------------------------------------------------------------
// Pool (8 lanes per (roi,bin)): lane j in 0..7.
// Stage 1: corner c=j&3, channel-half hf=j>>2 -> ONE half4 load from OM;
// butterfly xor 1,2 sums corners; xor 4 exchanges halves. Stage 2: bilinear
// on Fh2 (fragment-major layout), two half2 loads per lane, xor 4 combines.
// ---------------------------------------------------------------------------
__device__ __forceinline__ void bilin_setup(float y, float x,
                                            int& iy0, int& iy1, int& ix0, int& ix1,
                                            float& w00, float& w01, float& w10, float& w11) {
  const float y0f = floorf(y), x0f = floorf(x);
  const float wy = y - y0f, wx = x - x0f;   // unclamped, matches reference
  const int a = (int)y0f, b = (int)x0f;
  iy0 = min(max(a, 0), HH - 1);
  iy1 = min(max(a + 1, 0), HH - 1);
  ix0 = min(max(b, 0), WW - 1);
  ix1 = min(max(b + 1, 0), WW - 1);
  w00 = (1.f - wy) * (1.f - wx);
  w01 = (1.f - wy) * wx;
  w10 = wy * (1.f - wx);
  w11 = wy * wx;
}

__device__ __forceinline__ void pool_item8(const _Float16* __restrict__ Fh2,
                                           const float* __restrict__ R,
                                           const _Float16* __restrict__ OM,
                                           float* __restrict__ out, int tid) {
  const int j  = tid & 7;          // lane role within (roi,bin)
  const int nb = tid >> 3;
  const int n  = nb / NBIN;
  const int b  = nb - n * NBIN;
  const int bi = b / PSK;
  const int bj = b - bi * PSK;

  const float rx1 = R[n * 5 + 1], ry1 = R[n * 5 + 2];
  const float rx2 = R[n * 5 + 3], ry2 = R[n * 5 + 4];
  const float x1 = rx1 * (1.f / 16.f);
  const float y1 = ry1 * (1.f / 16.f);
  const float x2 = (rx2 + 1.f) * (1.f / 16.f);
  const float y2 = (ry2 + 1.f) * (1.f / 16.f);
  const float bw = (x2 - x1) * (1.f / 7.f);
  const float bh = (y2 - y1) * (1.f / 7.f);
  const float cx = x1 + ((float)bj + 0.5f) * bw;
  const float cy = y1 + ((float)bi + 0.5f) * bh;
  const float sxs = (rx2 - rx1 + 1.f) * (LAMDA / 16.f);
  const float sys = (ry2 - ry1 + 1.f) * (LAMDA / 16.f);

  // ---- stage 1: lane = (corner j&3, channel-half j>>2); one half4 load ----
  int iy0, iy1, ix0, ix1;
  float w00, w01, w10, w11;
  bilin_setup(cy, cx, iy0, iy1, ix0, ix1, w00, w01, w10, w11);

  const int c = j & 3;
  const int hf = j >> 2;
  const int cyi = (c >> 1) ? iy1 : iy0;
  const int cxi = (c & 1) ? ix1 : ix0;
  const float wq = (c == 0) ? w00 : (c == 1) ? w01 : (c == 2) ? w10 : w11;

  const size_t base = (size_t)(cyi * WW + cxi) * CC + (size_t)b * 8 + hf * 4;
  const half4v hv = *(const half4v*)(OM + base);

  float o4[4];
#pragma unroll
  for (int i = 0; i < 4; ++i) o4[i] = wq * (float)hv[i];
#pragma unroll
  for (int i = 0; i < 4; ++i) o4[i] += __shfl_xor(o4[i], 1);
#pragma unroll
  for (int i = 0; i < 4; ++i) o4[i] += __shfl_xor(o4[i], 2);
  float oth[4];
#pragma unroll
  for (int i = 0; i < 4; ++i) oth[i] = __shfl_xor(o4[i], 4);

  // lane holds channels [4hf..4hf+3] in o4, the other half in oth
  const int g = j & 3;
  const int i0 = (g & 1) * 2;              // (2g)&3
  const bool sel = ((g >> 1) == hf);
  const float ox = sel ? o4[i0]     : oth[i0];       // channel 2g
  const float oy = sel ? o4[i0 + 1] : oth[i0 + 1];   // channel 2g+1
  const float sx = cx + ox * sxs;
  const float sy = cy + oy * sys;

  // ---- stage 2: lane = (group g, y-half j>>2); two half2 loads from Fh2 ----
  int jy0, jy1, jx0, jx1;
  float u00, u01, u10, u11;
  bilin_setup(sy, sx, jy0, jy1, jx0, jx1, u00, u01, u10, u11);

  const int  yh = j >> 2;
  const int  jy = yh ? jy1 : jy0;
  const float ua = yh ? u10 : u00;   // weight at (jy, jx0)
  const float ub = yh ? u11 : u01;   // weight at (jy, jx1)

  const int c0 = b * 8 + 2 * g;
  const int kc = c0 >> 6, q = (c0 >> 3) & 7, e = c0 & 7;
  const _Float16* f2 = Fh2 + (((size_t)(jy + 1) * 7 + kc) * 8 + q) * (XP * 8) + e;
  const half2v qa = *(const half2v*)(f2 + (size_t)(jx0 + 1) * 8);
  const half2v qb = *(const half2v*)(f2 + (size_t)(jx1 + 1) * 8);

  float v0 = ua * (float)qa[0] + ub * (float)qb[0];
  float v1 = ua * (float)qa[1] + ub * (float)qb[1];
  v0 += __shfl_xor(v0, 4);
  v1 += __shfl_xor(v1, 4);

  // lane j<4 writes channel 2g, lane j>=4 writes channel 2g+1 (one store each)
  const float vout = yh ? v1 : v0;
  out[((size_t)n * 8 + 2 * g + yh) * NBIN + b] = vout;
}

// ---------------------------------------------------------------------------
// Cooperative kernel: prep -> grid.sync -> barrier-free conv (448 x 256).
// ---------------------------------------------------------------------------
__global__ __launch_bounds__(NTHR, 2)
void mega_kernel(const float* __restrict__ F, const float* __restrict__ Wt,
                 _Float16* __restrict__ OM,
                 _Float16* __restrict__ Fh2, _Float16* __restrict__ Btf) {
  __shared__ float tile[32][33];
  const int bid = blockIdx.x;
  const int t = threadIdx.x;
  cg::grid_group grid = cg::this_grid();

  prep_features(F, Fh2, bid * NTHR + t, GSTRIDE);
  prep_weights(Wt, Btf, tile, bid, t, NTHR, NBLK);

  __threadfence();
  grid.sync();

  // XCD-aware bijective swizzle (448 % 8 == 0): each XCD gets a contiguous
  // run of ~19 image rows -> A panels + all B fit its L2.
  const int bid2 = (bid & 7) * (NBLK / 8) + (bid >> 3);
  conv_dispatch(Fh2, Btf, OM, bid2, t);
}

__global__ __launch_bounds__(256)
void pool_kernel(const _Float16* __restrict__ Fh2, const float* __restrict__ R,
                 const _Float16* __restrict__ OM, float* __restrict__ out) {
  pool_item8(Fh2, R, OM, out, blockIdx.x * 256 + threadIdx.x);
}

// ---------------------------------------------------------------------------
// Non-coop fallback (same device code, separate launches)
// ---------------------------------------------------------------------------
__global__ __launch_bounds__(256)
void prep_kernel_sa(const float* __restrict__ F, const float* __restrict__ Wt,
                    _Float16* __restrict__ Fh2, _Float16* __restrict__ Btf) {
  __shared__ float tile[32][33];
  prep_features(F, Fh2, blockIdx.x * 256 + threadIdx.x, gridDim.x * 256);
  prep_weights(Wt, Btf, tile, blockIdx.x, threadIdx.x, 256, gridDim.x);
}

__global__ __launch_bounds__(NTHR, 2)
void conv_kernel_sa(const _Float16* __restrict__ Fh2, const _Float16* __restrict__ Btf,
                    _Float16* __restrict__ OM) {
  const int bid2 = (blockIdx.x & 7) * (NBLK / 8) + (blockIdx.x >> 3);
  conv_dispatch(Fh2, Btf, OM, bid2, threadIdx.x);
}

extern "C" void kernel_launch(void* const* d_in, const int* in_sizes, int n_in,
                              void* d_out, int out_size, void* d_ws, size_t ws_size,
                              hipStream_t stream) {
  const float* F  = (const float*)d_in[0];   // features [1,128,128,392] fp32
  const float* R  = (const float*)d_in[1];   // rois [2048,5] fp32
  const float* Wt = (const float*)d_in[2];   // conv_w [3,3,392,392] fp32
  float* out = (float*)d_out;                // [2048,8,7,7] fp32

  const size_t omBytes  = (size_t)NPIX * CC * sizeof(_Float16);        // 12.85 MB
  const size_t fh2Bytes = (size_t)FH2TOT * 8 * sizeof(_Float16);       // 15.14 MB
  // Btf: 3.23 MB; total ~31.2 MB

  _Float16* OM  = (_Float16*)d_ws;
  _Float16* Fh2 = (_Float16*)((char*)d_ws + omBytes);
  _Float16* Btf = (_Float16*)((char*)d_ws + omBytes + fh2Bytes);

  int maxBlk = 0;
  hipError_t qerr = hipOccupancyMaxActiveBlocksPerMultiprocessor(&maxBlk, mega_kernel, NTHR, 0);
  bool coopOk = (qerr == hipSuccess && maxBlk >= 2);

  if (coopOk) {
    void* args[] = {(void*)&F, (void*)&Wt, (void*)&OM, (void*)&Fh2, (void*)&Btf};
    hipError_t err = hipLaunchCooperativeKernel((const void*)mega_kernel,
                                                dim3(NBLK), dim3(NTHR),
                                                args, 0, stream);
    if (err != hipSuccess) {
      (void)hipGetLastError();
      coopOk = false;
    }
  }
  if (!coopOk) {
    prep_kernel_sa<<<2048, 256, 0, stream>>>(F, Wt, Fh2, Btf);
    conv_kernel_sa<<<NBLK, NTHR, 0, stream>>>(Fh2, Btf, OM);
  }

  pool_kernel<<<POOL8 / 256, 256, 0, stream>>>(Fh2, R, OM, out);
}